// Round 1
// baseline (10.080 us; speedup 1.0000x reference)
//
#include <hip/hip_runtime.h>

// Vibrato — but the reference's jnp.take uses ABSOLUTE indices idx[t,d] in [0,224],
// so out[b,c,t] = (sum of audio[b,c, 0..k-1]) / 220 with k = trunc(depth*lfo[t]).
// Only the first ~5 samples of each channel are ever read.
//
// We bit-replicate the float32 op chain of the JAX reference:
//   ts    = fl32(t / 44100.0)                       (arange f32 / python-float 44100.0, weak->f32)
//   w     = fl32(fl32(2*pi) * rate)                 (python float 2*pi weak-promoted to f32)
//   theta = fl32(w * ts)
//   s     = sinf32(theta)                            -> we compute via double sin, CR-rounded to f32
//   lfo   = fl32(0.5 * fl32(1.0 + s))
//   v     = fl32(depth * lfo)                        in [0, 5]
//   idx(d)= (int32) fl32(v + d)                      (the f32 add's rounding matters near integers!)
// Only d = 215..219 can yield idx >= 220 (nonzero delayed region).

__global__ __launch_bounds__(256) void Vibrato_90142773608915_kernel(
    const float* __restrict__ audio,   // [4, N] flattened (B=2, C=2)
    const float* __restrict__ depth_p, // scalar
    const float* __restrict__ rate_p,  // scalar
    float* __restrict__ out,           // [4, N]
    int N)
{
    int t = blockIdx.x * blockDim.x + threadIdx.x;
    if (t >= N) return;

    const float depth = depth_p[0];
    const float rate  = rate_p[0];

    const float TWO_PI_F = 0x1.921fb6p+2f;        // fl32(2*pi), matches JAX weak-type promotion
    float w     = TWO_PI_F * rate;                // f32 mul
    float ts    = (float)t / 44100.0f;            // f32 CR division (t < 2^24, exact in f32)
    float theta = w * ts;                         // f32 mul
    float s     = (float)sin((double)theta);      // correctly-rounded f32 sin
    float lfo   = 0.5f * (1.0f + s);              // f32 add, exact *0.5
    float v     = depth * lfo;                    // f32 mul, in [0, 5]

    float sums0 = 0.0f, sums1 = 0.0f, sums2 = 0.0f, sums3 = 0.0f;
    #pragma unroll
    for (int d = 215; d <= 219; ++d) {
        float fi = v + (float)d;                  // replicate idx = (v + d) f32 rounding
        int j = (int)fi - 220;                    // trunc toward zero (fi >= 0)
        if (j >= 0) {
            // ascending-d order == ascending-j order; zeros elsewhere don't affect rounding
            sums0 += audio[j];
            sums1 += audio[(size_t)N + j];
            sums2 += audio[2 * (size_t)N + j];
            sums3 += audio[3 * (size_t)N + j];
        }
    }

    out[t]                 = sums0 / 220.0f;
    out[(size_t)N + t]     = sums1 / 220.0f;
    out[2 * (size_t)N + t] = sums2 / 220.0f;
    out[3 * (size_t)N + t] = sums3 / 220.0f;
}

extern "C" void kernel_launch(void* const* d_in, const int* in_sizes, int n_in,
                              void* d_out, int out_size, void* d_ws, size_t ws_size,
                              hipStream_t stream) {
    const float* audio = (const float*)d_in[0];
    const float* depth = (const float*)d_in[1];
    const float* rate  = (const float*)d_in[2];
    float* out = (float*)d_out;

    int N = in_sizes[0] / 4;   // B*C = 2*2 = 4 channels
    int threads = 256;
    int blocks = (N + threads - 1) / threads;
    Vibrato_90142773608915_kernel<<<blocks, threads, 0, stream>>>(audio, depth, rate, out, N);
}